// Round 8
// baseline (268.575 us; speedup 1.0000x reference)
//
#include <hip/hip_runtime.h>
#include <hip/hip_fp16.h>
#include <stdint.h>

#define Bz 2
#define Tq 1024
#define Mm 1024
#define Hh 16
#define Ll 2048
#define Rr 3072

typedef __attribute__((ext_vector_type(8))) short bf16x8;
typedef __attribute__((ext_vector_type(4))) float f32x4;

typedef __attribute__((address_space(3))) uint8_t lds_u8_t;
typedef __attribute__((address_space(1))) uint8_t glb_u8_t;

__device__ __forceinline__ void gl2lds16(const void* g, void* l) {
  __builtin_amdgcn_global_load_lds((const glb_u8_t*)g, (lds_u8_t*)l, 16, 0, 0);
}

__device__ __forceinline__ unsigned short f2bf(float f) {
  unsigned int u = __builtin_bit_cast(unsigned int, f);
  u = u + 0x7fffu + ((u >> 16) & 1u);
  return (unsigned short)(u >> 16);
}
__device__ __forceinline__ float b2f(unsigned short s) {
  unsigned int u = ((unsigned int)s) << 16;
  return __builtin_bit_cast(float, u);
}
// packed f32x2 -> bf16x2 (RNE), gfx950; no builtin exists (T12/m240)
__device__ __forceinline__ unsigned int cvt_pk_bf16(float lo, float hi) {
  unsigned int r;
  asm volatile("v_cvt_pk_bf16_f32 %0, %1, %2" : "=v"(r) : "v"(lo), "v"(hi));
  return r;
}

// ------- prep (merged): values cast | pos cast | 5x W transpose -------------
__global__ __launch_bounds__(256) void k_prep2(
    const float* __restrict__ x, const float* __restrict__ mem,
    const float* __restrict__ pos,
    const float* __restrict__ w0, const float* __restrict__ w1,
    const float* __restrict__ w2, const float* __restrict__ w3,
    const float* __restrict__ w4,
    unsigned short* __restrict__ vin, unsigned short* __restrict__ pb,
    unsigned short* __restrict__ t0, unsigned short* __restrict__ t1,
    unsigned short* __restrict__ t2, unsigned short* __restrict__ t3,
    unsigned short* __restrict__ t4) {
  __shared__ float tile[64][65];
  int bid = blockIdx.x;
  if (bid < 4096) {
    int idx = bid * 256 + threadIdx.x;
    int e = idx << 2;
    int row = e >> 10, col = e & 1023;
    int b = row >> 11, l = row & 2047;
    const float* s = (l < Mm) ? (mem + (((size_t)b * Mm + l) << 10) + col)
                              : (x + (((size_t)b * Tq + (l - Mm)) << 10) + col);
    float4 v = *(const float4*)s;
    ushort4 o;
    o.x = f2bf(v.x); o.y = f2bf(v.y); o.z = f2bf(v.z); o.w = f2bf(v.w);
    *(ushort4*)(vin + e) = o;
  } else if (bid < 7168) {
    int idx = (bid - 4096) * 256 + threadIdx.x;
    int e = idx << 2;
    float4 v = *(const float4*)(pos + e);
    ushort4 t;
    t.x = f2bf(v.x); t.y = f2bf(v.y); t.z = f2bf(v.z); t.w = f2bf(v.w);
    *(ushort4*)(pb + e) = t;
  } else {
    int r3 = bid - 7168;
    int mz = r3 >> 8, rem = r3 & 255;
    const float* W;
    unsigned short* WT;
    switch (mz) {
      case 0: W = w0; WT = t0; break;
      case 1: W = w1; WT = t1; break;
      case 2: W = w2; WT = t2; break;
      case 3: W = w3; WT = t3; break;
      default: W = w4; WT = t4; break;
    }
    int k0 = (rem >> 4) * 64, n0 = (rem & 15) * 64;
    int tid = threadIdx.x;
    int rr = tid >> 4, c4 = (tid & 15) * 4;
#pragma unroll
    for (int it = 0; it < 4; ++it) {
      int r = rr + it * 16;
      float4 v = *(const float4*)(W + (size_t)(k0 + r) * 1024 + n0 + c4);
      tile[r][c4] = v.x; tile[r][c4 + 1] = v.y;
      tile[r][c4 + 2] = v.z; tile[r][c4 + 3] = v.w;
    }
    __syncthreads();
#pragma unroll
    for (int it = 0; it < 4; ++it) {
      int n = rr + it * 16;
      ushort4 o;
      o.x = f2bf(tile[c4 + 0][n]); o.y = f2bf(tile[c4 + 1][n]);
      o.z = f2bf(tile[c4 + 2][n]); o.w = f2bf(tile[c4 + 3][n]);
      *(ushort4*)(WT + (size_t)(n0 + n) * 1024 + k0 + c4) = o;
    }
  }
}

// ------- bf16 NT GEMM core, single-barrier pipelined, dbuf LDS (K=1024) -----
template <int RMAP>
__device__ __forceinline__ void gemm_pipe(const unsigned short* __restrict__ A,
                                          const unsigned short* __restrict__ Bt,
                                          int m0, int n0, unsigned short* As,
                                          unsigned short* Bs, f32x4 acc[4][4]) {
  const int tid = threadIdx.x;
  const int w = tid >> 6, lane = tid & 63;
  const int quad = lane >> 4, li = lane & 15;
  const int wr = w >> 1, wc = w & 1;
  f32x4 z = {0.f, 0.f, 0.f, 0.f};
#pragma unroll
  for (int mi = 0; mi < 4; ++mi)
#pragma unroll
    for (int ni = 0; ni < 4; ++ni) acc[mi][ni] = z;

  const int rs = lane >> 2;
  const int cs = lane & 3;

#pragma unroll
  for (int s = 0; s < 2; ++s) {
    int i = w * 2 + s;
    int r = i * 16 + rs;
    int c = cs ^ ((r >> 1) & 3);
    int ar = m0 + r;
    if (RMAP) ar = ar + 1024 + (ar & 1024);
    gl2lds16(A + (size_t)ar * 1024 + c * 8, (char*)As + i * 1024);
    gl2lds16(Bt + (size_t)(n0 + r) * 1024 + c * 8, (char*)Bs + i * 1024);
  }

  for (int k0 = 0; k0 < 1024; k0 += 32) {
    const int bo = ((k0 >> 5) & 1) * 8192;
    const int no = bo ^ 8192;
    __builtin_amdgcn_s_waitcnt(0x0F70);
    __syncthreads();
    if (k0 + 32 < 1024) {
#pragma unroll
      for (int s = 0; s < 2; ++s) {
        int i = w * 2 + s;
        int r = i * 16 + rs;
        int c = cs ^ ((r >> 1) & 3);
        int ar = m0 + r;
        if (RMAP) ar = ar + 1024 + (ar & 1024);
        gl2lds16(A + (size_t)ar * 1024 + k0 + 32 + c * 8,
                 (char*)As + no + i * 1024);
        gl2lds16(Bt + (size_t)(n0 + r) * 1024 + k0 + 32 + c * 8,
                 (char*)Bs + no + i * 1024);
      }
    }
    bf16x8 af[4], bfr[4];
#pragma unroll
    for (int mi = 0; mi < 4; ++mi) {
      int r = wr * 64 + mi * 16 + li;
      int ch = quad ^ ((r >> 1) & 3);
      af[mi] = *(const bf16x8*)((const char*)As + bo + r * 64 + ch * 16);
    }
#pragma unroll
    for (int ni = 0; ni < 4; ++ni) {
      int r = wc * 64 + ni * 16 + li;
      int ch = quad ^ ((r >> 1) & 3);
      bfr[ni] = *(const bf16x8*)((const char*)Bs + bo + r * 64 + ch * 16);
    }
#pragma unroll
    for (int mi = 0; mi < 4; ++mi)
#pragma unroll
      for (int ni = 0; ni < 4; ++ni)
        acc[mi][ni] = __builtin_amdgcn_mfma_f32_16x16x32_bf16(
            af[mi], bfr[ni], acc[mi][ni], 0, 0, 0);
  }
}

// fused projections
// R16: v-branch store coalesced -- re-stage the 128x128 v-tile through the
// dead As buffer ([64][128] bf16 = 8192 shorts exactly) in two 64-row passes,
// then write vtb rows as contiguous 64B/thread dwordx4 (was: 64-way-split
// 8B scatter, 4KB lane stride). Bank conflicts in this once-per-block
// epilogue are irrelevant.
__global__ __launch_bounds__(256) void k_proj(
    const unsigned short* __restrict__ Vin, const unsigned short* __restrict__ Pb,
    const unsigned short* __restrict__ WqT, const unsigned short* __restrict__ WkT,
    const unsigned short* __restrict__ WvT, const unsigned short* __restrict__ WrT,
    unsigned short* __restrict__ qb, unsigned short* __restrict__ kb,
    unsigned short* __restrict__ vtb, unsigned short* __restrict__ rkb) {
  __shared__ unsigned short As[2 * 128 * 32];
  __shared__ unsigned short Bs[2 * 128 * 32];
  const int t = blockIdx.x;
  const int tid = threadIdx.x, w = tid >> 6, lane = tid & 63;
  const int quad = lane >> 4, li = lane & 15, wr = w >> 1, wc = w & 1;
  f32x4 acc[4][4];

  if (t < 256) {  // k
    int m0 = (t >> 3) * 128, n0 = (t & 7) * 128;
    gemm_pipe<0>(Vin, WkT, m0, n0, As, Bs, acc);
#pragma unroll
    for (int mi = 0; mi < 4; ++mi)
#pragma unroll
      for (int ni = 0; ni < 4; ++ni)
#pragma unroll
        for (int reg = 0; reg < 4; ++reg) {
          int rrow = m0 + wr * 64 + mi * 16 + quad * 4 + reg;
          int cc = n0 + wc * 64 + ni * 16 + li;
          kb[(size_t)rrow * 1024 + cc] = f2bf(acc[mi][ni][reg]);
        }
  } else if (t < 512) {  // v -> vtb, coalesced two-pass via As re-stage
    int tt = t - 256;
    int m0 = (tt >> 3) * 128, n0 = (tt & 7) * 128;
    gemm_pipe<0>(Vin, WvT, m0, n0, As, Bs, acc);
    unsigned short* T = As;  // [64][128], As dead after gemm_pipe
    int b = m0 >> 11, l0b = m0 & 2047;
    int rr2 = tid >> 2, q2 = tid & 3;
#pragma unroll
    for (int p = 0; p < 2; ++p) {
      __syncthreads();
      if (wc == p) {
#pragma unroll
        for (int mi = 0; mi < 4; ++mi)
#pragma unroll
          for (int ni = 0; ni < 4; ++ni) {
            int ccl = ni * 16 + li;
            int ll = wr * 64 + mi * 16 + quad * 4;
            ushort4 o;
            o.x = f2bf(acc[mi][ni][0]); o.y = f2bf(acc[mi][ni][1]);
            o.z = f2bf(acc[mi][ni][2]); o.w = f2bf(acc[mi][ni][3]);
            *(ushort4*)(T + ccl * 128 + ll) = o;
          }
      }
      __syncthreads();
      const uint4* src = (const uint4*)(T + rr2 * 128 + q2 * 32);
      uint4 v0 = src[0], v1 = src[1], v2 = src[2], v3 = src[3];
      uint4* dp = (uint4*)(vtb +
          ((size_t)(b * 1024 + n0 + p * 64 + rr2)) * Ll + l0b + q2 * 32);
      dp[0] = v0; dp[1] = v1; dp[2] = v2; dp[3] = v3;
    }
  } else if (t < 640) {  // q raw
    int tt = t - 512;
    int m0 = (tt >> 3) * 128, n0 = (tt & 7) * 128;
    gemm_pipe<1>(Vin, WqT, m0, n0, As, Bs, acc);
#pragma unroll
    for (int mi = 0; mi < 4; ++mi)
#pragma unroll
      for (int ni = 0; ni < 4; ++ni)
#pragma unroll
        for (int reg = 0; reg < 4; ++reg) {
          int rrow = m0 + wr * 64 + mi * 16 + quad * 4 + reg;
          int cc = n0 + wc * 64 + ni * 16 + li;
          qb[(size_t)rrow * 1024 + cc] = f2bf(acc[mi][ni][reg]);
        }
  } else {  // rk
    int tt = t - 640;
    int m0 = (tt >> 3) * 128, n0 = (tt & 7) * 128;
    gemm_pipe<0>(Pb, WrT, m0, n0, As, Bs, acc);
#pragma unroll
    for (int mi = 0; mi < 4; ++mi)
#pragma unroll
      for (int ni = 0; ni < 4; ++ni)
#pragma unroll
        for (int reg = 0; reg < 4; ++reg) {
          int rrow = m0 + wr * 64 + mi * 16 + quad * 4 + reg;
          int cc = n0 + wc * 64 + ni * 16 + li;
          rkb[(size_t)rrow * 1024 + cc] = f2bf(acc[mi][ni][reg]);
        }
  }
}

// output projection
// R16: retiled 64x128 -> 64x64, grid (32,16) = 512 blocks = 2 blocks/CU
// (was 256 = exactly 1/CU: every k-step's vmcnt(0) drain fully exposed, no
// co-resident block to overlap). 16KB LDS, acc[2][2], 4 MFMA/wave/k-step.
__global__ __launch_bounds__(256) void k_gemm_out64(
    const unsigned short* __restrict__ attnb, const unsigned short* __restrict__ WoT,
    float* __restrict__ out) {
  __shared__ unsigned short As[2 * 64 * 32];
  __shared__ unsigned short Bs[2 * 64 * 32];
  int m0 = blockIdx.x * 64, n0 = blockIdx.y * 64;
  const int tid = threadIdx.x, w = tid >> 6, lane = tid & 63;
  const int quad = lane >> 4, li = lane & 15, wr = w >> 1, wc = w & 1;
  f32x4 z = {0.f, 0.f, 0.f, 0.f};
  f32x4 acc[2][2];
#pragma unroll
  for (int mi = 0; mi < 2; ++mi)
#pragma unroll
    for (int ni = 0; ni < 2; ++ni) acc[mi][ni] = z;
  const int rs = lane >> 2, cs = lane & 3;

  // preload k0=0: per warp 16 rows x 64B = 1KB each for A and B
  {
    int r = w * 16 + rs;
    int c = cs ^ ((r >> 1) & 3);
    gl2lds16(attnb + (size_t)(m0 + r) * 1024 + c * 8, (char*)As + w * 1024);
    gl2lds16(WoT + (size_t)(n0 + r) * 1024 + c * 8, (char*)Bs + w * 1024);
  }

  for (int k0 = 0; k0 < 1024; k0 += 32) {
    const int bo = ((k0 >> 5) & 1) * 4096;
    __builtin_amdgcn_s_waitcnt(0x0F70);
    __syncthreads();
    if (k0 + 32 < 1024) {
      int r = w * 16 + rs;
      int c = cs ^ ((r >> 1) & 3);
      gl2lds16(attnb + (size_t)(m0 + r) * 1024 + k0 + 32 + c * 8,
               (char*)As + (bo ^ 4096) + w * 1024);
      gl2lds16(WoT + (size_t)(n0 + r) * 1024 + k0 + 32 + c * 8,
               (char*)Bs + (bo ^ 4096) + w * 1024);
    }
    bf16x8 af[2], bfr[2];
#pragma unroll
    for (int mi = 0; mi < 2; ++mi) {
      int r = wr * 32 + mi * 16 + li;
      int ch = quad ^ ((r >> 1) & 3);
      af[mi] = *(const bf16x8*)((const char*)As + bo + r * 64 + ch * 16);
    }
#pragma unroll
    for (int ni = 0; ni < 2; ++ni) {
      int r = wc * 32 + ni * 16 + li;
      int ch = quad ^ ((r >> 1) & 3);
      bfr[ni] = *(const bf16x8*)((const char*)Bs + bo + r * 64 + ch * 16);
    }
#pragma unroll
    for (int mi = 0; mi < 2; ++mi)
#pragma unroll
      for (int ni = 0; ni < 2; ++ni)
        acc[mi][ni] = __builtin_amdgcn_mfma_f32_16x16x32_bf16(
            af[mi], bfr[ni], acc[mi][ni], 0, 0, 0);
  }
#pragma unroll
  for (int mi = 0; mi < 2; ++mi)
#pragma unroll
    for (int ni = 0; ni < 2; ++ni)
#pragma unroll
      for (int reg = 0; reg < 4; ++reg) {
        int rrow = m0 + wr * 32 + mi * 16 + quad * 4 + reg;
        int cc = n0 + wc * 32 + ni * 16 + li;
        out[(size_t)rrow * 1024 + cc] = acc[mi][ni][reg];
      }
}

// ---------------- flash attention (R15 best: 77.4us, untouched) -------------
__global__ __launch_bounds__(512, 4) void k_attn(
    const unsigned short* __restrict__ qb, const float* __restrict__ rwb,
    const float* __restrict__ rrb,
    const unsigned short* __restrict__ kb, const unsigned short* __restrict__ vt,
    const unsigned short* __restrict__ rkb, const float* __restrict__ maskf,
    unsigned short* __restrict__ attnb) {
  // LDS map (bytes):
  //   [0,16384)      KS: grp*8192 + buf*4096   (32 j-rows x 64 k, swizzled)
  //   [16384,32768)  VS: grp*8192 + buf*4096   (64 dv-rows x 32 j, swizzled)
  //   [32768,65536)  RS: grp*16384             (128-row ring x 64 k, swizzled)
  //   [65536,75776)  Sb: warp*1280             (16 x 40 half, stride 40)
  //   red = [32768, 53248) reused for cross-group reduction (RS dead by then)
  __shared__ __align__(16) uint8_t lds[75776];

  const int tid = threadIdx.x;
  const int w = tid >> 6, lane = tid & 63;
  const int quad = lane >> 4, li = lane & 15;
  const int wq = w & 3, grp = w >> 2;
  const int srow = lane >> 3, scs = lane & 7;
  // XCD-aware regroup (bijective): 16 qt-blocks of one (b,h) -> one XCD.
  const int flat = blockIdx.x + 16 * blockIdx.y + 256 * blockIdx.z;
  const int qt = (flat >> 3) & 15;
  const int g = 4 * (flat & 7) + (flat >> 7);
  const int h = g & 15, b = g >> 4;
  const int t0blk = qt * 64;
  const int t0w = t0blk + wq * 16;
  const int rboff = 48 - 16 * wq;
  const int rbase0 = Tq - t0blk - 63;
  const int jbase = grp * 1024;

  unsigned short* KS = (unsigned short*)(lds + grp * 8192);
  unsigned short* VS = (unsigned short*)(lds + 16384 + grp * 8192);
  unsigned short* RS = (unsigned short*)(lds + 32768 + grp * 16384);
  unsigned short* pw = (unsigned short*)(lds + 65536 + w * 1280);
  float* red = (float*)(lds + 32768);

  const unsigned short* kbase = kb + ((size_t)(b * Ll + jbase) * Hh + h) * 64;
  const unsigned short* vbase = vt + ((size_t)((b * Hh + h) * 64)) * Ll + jbase;
  const unsigned short* rkbase = rkb + (size_t)h * 64;
  const float* mrowf = maskf + ((size_t)(b * Tq + t0w + li)) * Ll + jbase;

  // q + bias fragments (both groups load the same rows; redundant but cheap)
  bf16x8 aqw[2], aqr[2];
  {
    const unsigned short* p1 = qb + ((size_t)((b * Tq + t0w + li) * Hh + h)) * 64;
#pragma unroll
    for (int ks = 0; ks < 2; ++ks) {
      bf16x8 qf = *(const bf16x8*)(p1 + ks * 32 + quad * 8);
      const float* wp = rwb + h * 64 + ks * 32 + quad * 8;
      const float* rp = rrb + h * 64 + ks * 32 + quad * 8;
      float4 w0 = *(const float4*)wp, w1 = *(const float4*)(wp + 4);
      float4 r0 = *(const float4*)rp, r1 = *(const float4*)(rp + 4);
      float wv[8] = {w0.x, w0.y, w0.z, w0.w, w1.x, w1.y, w1.z, w1.w};
      float rv[8] = {r0.x, r0.y, r0.z, r0.w, r1.x, r1.y, r1.z, r1.w};
#pragma unroll
      for (int i2 = 0; i2 < 8; ++i2) {
        float qv = b2f((unsigned short)qf[i2]);
        aqw[ks][i2] = (short)f2bf(qv + wv[i2]);
        aqr[ks][i2] = (short)f2bf(qv + rv[i2]);
      }
    }
  }

  f32x4 z = {0.f, 0.f, 0.f, 0.f};
  f32x4 o[4];
  o[0] = z; o[1] = z; o[2] = z; o[3] = z;
  f32x4 ol = z;
  float nmf[8] = {0.f, 0.f, 0.f, 0.f, 0.f, 0.f, 0.f, 0.f};

  const float SC = 0.125f * 1.4426950408889634f;
  const float BIGM = 1.442695e30f;
  const short oneb = 0x3F80;
  const bf16x8 onesf = {oneb, oneb, oneb, oneb, oneb, oneb, oneb, oneb};

  int srcl[4];
#pragma unroll
  for (int reg = 0; reg < 4; ++reg) {
    int row = quad * 4 + reg;
    srcl[reg] = (lane & 48) + ((li + row + 1) & 15);
  }

  // finish tile whose S sits in pw: S->P (exp + mask), ol + PV MFMA cluster.
  auto finish = [&](const unsigned short* VsP, const float (&mv)[8]) {
    bf16x8 sv = *(const bf16x8*)(pw + li * 40 + quad * 8);
    float p[8];
#pragma unroll
    for (int i2 = 0; i2 < 8; ++i2) {
      float sf = __half2float(__builtin_bit_cast(__half, (unsigned short)sv[i2]));
      float mvneg = fmaf(mv[i2], BIGM, -BIGM);  // -(1-m)*BIGM
      p[i2] = exp2f(fmaf(sf, SC, mvneg));
    }
    int4 pk;
    pk.x = (int)cvt_pk_bf16(p[0], p[1]);
    pk.y = (int)cvt_pk_bf16(p[2], p[3]);
    pk.z = (int)cvt_pk_bf16(p[4], p[5]);
    pk.w = (int)cvt_pk_bf16(p[6], p[7]);
    bf16x8 apv = __builtin_bit_cast(bf16x8, pk);
    __builtin_amdgcn_s_setprio(1);
    ol = __builtin_amdgcn_mfma_f32_16x16x32_bf16(apv, onesf, ol, 0, 0, 0);
#pragma unroll
    for (int nt = 0; nt < 4; ++nt) {
      int dv = nt * 16 + li;
      int ch = quad ^ ((dv >> 1) & 3);  // V-fix: perm=(dv>>1)&3
      bf16x8 vf = *(const bf16x8*)(VsP + dv * 32 + ch * 8);
      o[nt] = __builtin_amdgcn_mfma_f32_16x16x32_bf16(apv, vf, o[nt], 0, 0, 0);
    }
    __builtin_amdgcn_s_setprio(0);
  };

  // prologue: R ring rows u in [0,96); K[0]. V is lag-1 (loaded in-loop).
#pragma unroll
  for (int pass = 0; pass < 3; ++pass) {
    int u = pass * 32 + wq * 8 + srow;
    int gr = rbase0 + jbase + u;
    if (gr > Rr - 1) gr = Rr - 1;
    int c = scs ^ srow;
    gl2lds16(rkbase + (size_t)gr * 1024 + c * 8, RS + (pass * 32 + wq * 8) * 64);
  }
  {
    int r = wq * 8 + srow;
    int c = scs ^ srow;
    gl2lds16(kbase + (size_t)r * 1024 + c * 8, KS + wq * 512);
  }

  for (int jt = 0; jt < 32; ++jt) {
    const int jloc = jt * 32;
    __builtin_amdgcn_s_waitcnt(0x0F70);  // vmcnt(0)
    __syncthreads();
    // ---- prefetch: K[jt+1], R[jloc+96,+128) (jt<31); V[jt] (always) ----
    if (jt < 31) {
      {
        int r = wq * 8 + srow;
        int c = scs ^ srow;
        gl2lds16(kbase + (size_t)(jloc + 32 + r) * 1024 + c * 8,
                 KS + (((jt + 1) & 1) * 2048) + wq * 512);
      }
      {
        int u = jloc + 96 + wq * 8 + srow;
        int gr = rbase0 + jbase + u;
        if (gr > Rr - 1) gr = Rr - 1;
        int c = scs ^ srow;
        gl2lds16(rkbase + (size_t)gr * 1024 + c * 8,
                 RS + ((jloc + 96 + wq * 8) & 127) * 64);
      }
    }
    {
      int dv = wq * 16 + (lane >> 2);
      int c = (lane & 3) ^ ((dv >> 1) & 3);  // V-fix: perm=(dv>>1)&3
      gl2lds16(vbase + (size_t)dv * Ll + jloc + c * 8,
               VS + ((jt & 1) * 2048) + wq * 512);
    }
    asm volatile("" ::: "memory");
    // ---- QK^T + rel for tile jt (covers pw write->read turnaround) ----
    const unsigned short* KsC = KS + (jt & 1) * 2048;
    f32x4 sc[2];
    sc[0] = z; sc[1] = z;
    __builtin_amdgcn_s_setprio(1);
#pragma unroll
    for (int ks = 0; ks < 2; ++ks)
#pragma unroll
      for (int nt = 0; nt < 2; ++nt) {
        int j = nt * 16 + li;
        int ch = (ks * 4 + quad) ^ (j & 7);
        bf16x8 kf = *(const bf16x8*)(KsC + j * 64 + ch * 8);
        sc[nt] = __builtin_amdgcn_mfma_f32_16x16x32_bf16(aqw[ks], kf, sc[nt], 0, 0, 0);
      }
    f32x4 bd[3];
    bd[0] = z; bd[1] = z; bd[2] = z;
#pragma unroll
    for (int ks = 0; ks < 2; ++ks)
#pragma unroll
      for (int nt = 0; nt < 3; ++nt) {
        int pr = (rboff + nt * 16 + li + jloc) & 127;
        int ch = (ks * 4 + quad) ^ (pr & 7);
        bf16x8 rf = *(const bf16x8*)(RS + pr * 64 + ch * 8);
        bd[nt] = __builtin_amdgcn_mfma_f32_16x16x32_bf16(aqr[ks], rf, bd[nt], 0, 0, 0);
      }
    __builtin_amdgcn_s_setprio(0);
    // ---- finish tile jt-1 (S read from pw, written a full iter ago) ----
    if (jt > 0) finish(VS + ((jt - 1) & 1) * 2048, nmf);
    // mask (f32) for tile jt: raw loads register-lagged, consumed at finish
    // in jt+1 (full-iteration latency cover, WAR-safe)
    {
      float4 m0 = *(const float4*)(mrowf + jloc + quad * 8);
      float4 m1 = *(const float4*)(mrowf + jloc + quad * 8 + 4);
      nmf[0] = m0.x; nmf[1] = m0.y; nmf[2] = m0.z; nmf[3] = m0.w;
      nmf[4] = m1.x; nmf[5] = m1.y; nmf[6] = m1.z; nmf[7] = m1.w;
    }
    // ---- rel-shift combine + write S(jt) into pw ----
    float rot[2][4];
#pragma unroll
    for (int nt = 0; nt < 2; ++nt)
#pragma unroll
      for (int reg = 0; reg < 4; ++reg)
        rot[nt][reg] = __shfl(sc[nt][reg], srcl[reg], 64);
#pragma unroll
    for (int nt = 0; nt < 3; ++nt)
#pragma unroll
      for (int reg = 0; reg < 4; ++reg) {
        int row = quad * 4 + reg;
        int jj = nt * 16 + li + row - 15;
        int nthi = (nt > 1) ? 0 : nt;
        int ntlo = (nt == 0) ? 0 : (nt - 1);
        float val = ((li + row) >= 15) ? rot[nthi][reg] : rot[ntlo][reg];
        float s = val + bd[nt][reg];
        if ((unsigned)jj < 32u)
          pw[row * 40 + jj] = __builtin_bit_cast(unsigned short, __float2half(s));
      }
  }
  // epilogue: drain V[31]+mask, finish tile 31
  __builtin_amdgcn_s_waitcnt(0x0F70);
  __syncthreads();
  finish(VS + 2048, nmf);

  // ---- cross-group reduction (red overlays RS region; RS dead) ----
  if (grp == 1) {
    float* rp = red + (size_t)(wq * 64 + lane) * 20;
#pragma unroll
    for (int nt = 0; nt < 4; ++nt)
#pragma unroll
      for (int reg = 0; reg < 4; ++reg) rp[nt * 4 + reg] = o[nt][reg];
#pragma unroll
    for (int reg = 0; reg < 4; ++reg) rp[16 + reg] = ol[reg];
  }
  __syncthreads();
  if (grp == 0) {
    const float* rp = red + (size_t)(wq * 64 + lane) * 20;
    float inv[4];
#pragma unroll
    for (int reg = 0; reg < 4; ++reg) inv[reg] = 1.0f / (ol[reg] + rp[16 + reg]);
#pragma unroll
    for (int nt = 0; nt < 4; ++nt)
#pragma unroll
      for (int reg = 0; reg < 4; ++reg) {
        int trow = t0w + quad * 4 + reg;
        float val = (o[nt][reg] + rp[nt * 4 + reg]) * inv[reg];
        attnb[((size_t)(b * Tq + trow)) * 1024 + h * 64 + nt * 16 + li] = f2bf(val);
      }
  }
}

extern "C" void kernel_launch(void* const* d_in, const int* in_sizes, int n_in,
                              void* d_out, int out_size, void* d_ws, size_t ws_size,
                              hipStream_t stream) {
  const float* x = (const float*)d_in[0];
  const float* mask = (const float*)d_in[1];
  const float* pos = (const float*)d_in[2];
  const float* mem = (const float*)d_in[3];
  const float* Wq = (const float*)d_in[4];
  const float* Wk = (const float*)d_in[5];
  const float* Wv = (const float*)d_in[6];
  const float* Wr = (const float*)d_in[7];
  const float* rwb = (const float*)d_in[8];
  const float* rrb = (const float*)d_in[9];
  const float* Wo = (const float*)d_in[10];
  float* out = (float*)d_out;

  uint8_t* ws = (uint8_t*)d_ws;
  const size_t MB = 1024 * 1024;
  unsigned short* Vinb = (unsigned short*)(ws + 0);
  unsigned short* WqT = (unsigned short*)(ws + 8 * MB);
  unsigned short* WkT = (unsigned short*)(ws + 10 * MB);
  unsigned short* WvT = (unsigned short*)(ws + 12 * MB);
  unsigned short* WrT = (unsigned short*)(ws + 14 * MB);
  unsigned short* WoT = (unsigned short*)(ws + 16 * MB);
  unsigned short* Pb = (unsigned short*)(ws + 18 * MB);
  unsigned short* qb = (unsigned short*)(ws + 24 * MB);
  unsigned short* kb = (unsigned short*)(ws + 32 * MB);
  unsigned short* vtb = (unsigned short*)(ws + 40 * MB);
  unsigned short* rkb = (unsigned short*)(ws + 48 * MB);
  unsigned short* attnb = (unsigned short*)(ws + 19 * MB);

  hipLaunchKernelGGL(k_prep2, dim3(8448), dim3(256), 0, stream,
                     x, mem, pos, Wq, Wk, Wv, Wr, Wo,
                     Vinb, Pb, WqT, WkT, WvT, WrT, WoT);
  hipLaunchKernelGGL(k_proj, dim3(832), dim3(256), 0, stream,
                     Vinb, Pb, WqT, WkT, WvT, WrT, qb, kb, vtb, rkb);
  hipLaunchKernelGGL(k_attn, dim3(16, 16, 2), dim3(512), 0, stream,
                     qb, rwb, rrb, kb, vtb, rkb, mask, attnb);
  hipLaunchKernelGGL(k_gemm_out64, dim3(32, 16), dim3(256), 0, stream,
                     attnb, WoT, out);
}

// Round 9
// 239.691 us; speedup vs baseline: 1.1205x; 1.1205x over previous
//
#include <hip/hip_runtime.h>
#include <hip/hip_fp16.h>
#include <stdint.h>

#define Bz 2
#define Tq 1024
#define Mm 1024
#define Hh 16
#define Ll 2048
#define Rr 3072

typedef __attribute__((ext_vector_type(8))) short bf16x8;
typedef __attribute__((ext_vector_type(4))) float f32x4;

typedef __attribute__((address_space(3))) uint8_t lds_u8_t;
typedef __attribute__((address_space(1))) uint8_t glb_u8_t;

__device__ __forceinline__ void gl2lds16(const void* g, void* l) {
  __builtin_amdgcn_global_load_lds((const glb_u8_t*)g, (lds_u8_t*)l, 16, 0, 0);
}

__device__ __forceinline__ unsigned short f2bf(float f) {
  unsigned int u = __builtin_bit_cast(unsigned int, f);
  u = u + 0x7fffu + ((u >> 16) & 1u);
  return (unsigned short)(u >> 16);
}
__device__ __forceinline__ float b2f(unsigned short s) {
  unsigned int u = ((unsigned int)s) << 16;
  return __builtin_bit_cast(float, u);
}
// packed f32x2 -> bf16x2 (RNE), gfx950; no builtin exists (T12/m240)
__device__ __forceinline__ unsigned int cvt_pk_bf16(float lo, float hi) {
  unsigned int r;
  asm volatile("v_cvt_pk_bf16_f32 %0, %1, %2" : "=v"(r) : "v"(lo), "v"(hi));
  return r;
}

// ------- prep (merged): values cast | pos cast | 5x W transpose -------------
__global__ __launch_bounds__(256) void k_prep2(
    const float* __restrict__ x, const float* __restrict__ mem,
    const float* __restrict__ pos,
    const float* __restrict__ w0, const float* __restrict__ w1,
    const float* __restrict__ w2, const float* __restrict__ w3,
    const float* __restrict__ w4,
    unsigned short* __restrict__ vin, unsigned short* __restrict__ pb,
    unsigned short* __restrict__ t0, unsigned short* __restrict__ t1,
    unsigned short* __restrict__ t2, unsigned short* __restrict__ t3,
    unsigned short* __restrict__ t4) {
  __shared__ float tile[64][65];
  int bid = blockIdx.x;
  if (bid < 4096) {
    int idx = bid * 256 + threadIdx.x;
    int e = idx << 2;
    int row = e >> 10, col = e & 1023;
    int b = row >> 11, l = row & 2047;
    const float* s = (l < Mm) ? (mem + (((size_t)b * Mm + l) << 10) + col)
                              : (x + (((size_t)b * Tq + (l - Mm)) << 10) + col);
    float4 v = *(const float4*)s;
    ushort4 o;
    o.x = f2bf(v.x); o.y = f2bf(v.y); o.z = f2bf(v.z); o.w = f2bf(v.w);
    *(ushort4*)(vin + e) = o;
  } else if (bid < 7168) {
    int idx = (bid - 4096) * 256 + threadIdx.x;
    int e = idx << 2;
    float4 v = *(const float4*)(pos + e);
    ushort4 t;
    t.x = f2bf(v.x); t.y = f2bf(v.y); t.z = f2bf(v.z); t.w = f2bf(v.w);
    *(ushort4*)(pb + e) = t;
  } else {
    int r3 = bid - 7168;
    int mz = r3 >> 8, rem = r3 & 255;
    const float* W;
    unsigned short* WT;
    switch (mz) {
      case 0: W = w0; WT = t0; break;
      case 1: W = w1; WT = t1; break;
      case 2: W = w2; WT = t2; break;
      case 3: W = w3; WT = t3; break;
      default: W = w4; WT = t4; break;
    }
    int k0 = (rem >> 4) * 64, n0 = (rem & 15) * 64;
    int tid = threadIdx.x;
    int rr = tid >> 4, c4 = (tid & 15) * 4;
#pragma unroll
    for (int it = 0; it < 4; ++it) {
      int r = rr + it * 16;
      float4 v = *(const float4*)(W + (size_t)(k0 + r) * 1024 + n0 + c4);
      tile[r][c4] = v.x; tile[r][c4 + 1] = v.y;
      tile[r][c4 + 2] = v.z; tile[r][c4 + 3] = v.w;
    }
    __syncthreads();
#pragma unroll
    for (int it = 0; it < 4; ++it) {
      int n = rr + it * 16;
      ushort4 o;
      o.x = f2bf(tile[c4 + 0][n]); o.y = f2bf(tile[c4 + 1][n]);
      o.z = f2bf(tile[c4 + 2][n]); o.w = f2bf(tile[c4 + 3][n]);
      *(ushort4*)(WT + (size_t)(n0 + n) * 1024 + k0 + c4) = o;
    }
  }
}

// ------- bf16 NT GEMM core, single-barrier pipelined, dbuf LDS (K=1024) -----
template <int RMAP>
__device__ __forceinline__ void gemm_pipe(const unsigned short* __restrict__ A,
                                          const unsigned short* __restrict__ Bt,
                                          int m0, int n0, unsigned short* As,
                                          unsigned short* Bs, f32x4 acc[4][4]) {
  const int tid = threadIdx.x;
  const int w = tid >> 6, lane = tid & 63;
  const int quad = lane >> 4, li = lane & 15;
  const int wr = w >> 1, wc = w & 1;
  f32x4 z = {0.f, 0.f, 0.f, 0.f};
#pragma unroll
  for (int mi = 0; mi < 4; ++mi)
#pragma unroll
    for (int ni = 0; ni < 4; ++ni) acc[mi][ni] = z;

  const int rs = lane >> 2;
  const int cs = lane & 3;

#pragma unroll
  for (int s = 0; s < 2; ++s) {
    int i = w * 2 + s;
    int r = i * 16 + rs;
    int c = cs ^ ((r >> 1) & 3);
    int ar = m0 + r;
    if (RMAP) ar = ar + 1024 + (ar & 1024);
    gl2lds16(A + (size_t)ar * 1024 + c * 8, (char*)As + i * 1024);
    gl2lds16(Bt + (size_t)(n0 + r) * 1024 + c * 8, (char*)Bs + i * 1024);
  }

  for (int k0 = 0; k0 < 1024; k0 += 32) {
    const int bo = ((k0 >> 5) & 1) * 8192;
    const int no = bo ^ 8192;
    __builtin_amdgcn_s_waitcnt(0x0F70);
    __syncthreads();
    if (k0 + 32 < 1024) {
#pragma unroll
      for (int s = 0; s < 2; ++s) {
        int i = w * 2 + s;
        int r = i * 16 + rs;
        int c = cs ^ ((r >> 1) & 3);
        int ar = m0 + r;
        if (RMAP) ar = ar + 1024 + (ar & 1024);
        gl2lds16(A + (size_t)ar * 1024 + k0 + 32 + c * 8,
                 (char*)As + no + i * 1024);
        gl2lds16(Bt + (size_t)(n0 + r) * 1024 + k0 + 32 + c * 8,
                 (char*)Bs + no + i * 1024);
      }
    }
    bf16x8 af[4], bfr[4];
#pragma unroll
    for (int mi = 0; mi < 4; ++mi) {
      int r = wr * 64 + mi * 16 + li;
      int ch = quad ^ ((r >> 1) & 3);
      af[mi] = *(const bf16x8*)((const char*)As + bo + r * 64 + ch * 16);
    }
#pragma unroll
    for (int ni = 0; ni < 4; ++ni) {
      int r = wc * 64 + ni * 16 + li;
      int ch = quad ^ ((r >> 1) & 3);
      bfr[ni] = *(const bf16x8*)((const char*)Bs + bo + r * 64 + ch * 16);
    }
#pragma unroll
    for (int mi = 0; mi < 4; ++mi)
#pragma unroll
      for (int ni = 0; ni < 4; ++ni)
        acc[mi][ni] = __builtin_amdgcn_mfma_f32_16x16x32_bf16(
            af[mi], bfr[ni], acc[mi][ni], 0, 0, 0);
  }
}

// fused projections
// R17: (a) v-branch store reverted to R7 scatter (R8's LDS re-stage pushed
//     VGPR to 132 -> occupancy cliff, k_proj 80us; regalloc is per-kernel so
//     all branches paid). (b) XCD regroup (T1, proven on k_attn R2): the 8
//     blocks sharing an A-panel are made congruent mod 8 -> one XCD's L2.
//     Per segment of size 8*8*K: a=f&7, n=(f>>3)&7, c=f>>6; m=K*a+c
//     (bijective, c<K). Segment offsets 0/256/512/640 are ==0 mod 8.
__global__ __launch_bounds__(256) void k_proj(
    const unsigned short* __restrict__ Vin, const unsigned short* __restrict__ Pb,
    const unsigned short* __restrict__ WqT, const unsigned short* __restrict__ WkT,
    const unsigned short* __restrict__ WvT, const unsigned short* __restrict__ WrT,
    unsigned short* __restrict__ qb, unsigned short* __restrict__ kb,
    unsigned short* __restrict__ vtb, unsigned short* __restrict__ rkb) {
  __shared__ unsigned short As[2 * 128 * 32];
  __shared__ unsigned short Bs[2 * 128 * 32];
  const int t = blockIdx.x;
  const int tid = threadIdx.x, w = tid >> 6, lane = tid & 63;
  const int quad = lane >> 4, li = lane & 15, wr = w >> 1, wc = w & 1;
  f32x4 acc[4][4];

  if (t < 256) {  // k: 32 m-tiles x 8 n-tiles
    int a = t & 7, n = (t >> 3) & 7, c = t >> 6;
    int m0 = (4 * a + c) * 128, n0 = n * 128;
    gemm_pipe<0>(Vin, WkT, m0, n0, As, Bs, acc);
#pragma unroll
    for (int mi = 0; mi < 4; ++mi)
#pragma unroll
      for (int ni = 0; ni < 4; ++ni)
#pragma unroll
        for (int reg = 0; reg < 4; ++reg) {
          int rrow = m0 + wr * 64 + mi * 16 + quad * 4 + reg;
          int cc = n0 + wc * 64 + ni * 16 + li;
          kb[(size_t)rrow * 1024 + cc] = f2bf(acc[mi][ni][reg]);
        }
  } else if (t < 512) {  // v: 32 m x 8 n, R7 scatter store
    int f = t - 256;
    int a = f & 7, n = (f >> 3) & 7, c = f >> 6;
    int m0 = (4 * a + c) * 128, n0 = n * 128;
    gemm_pipe<0>(Vin, WvT, m0, n0, As, Bs, acc);
#pragma unroll
    for (int mi = 0; mi < 4; ++mi)
#pragma unroll
      for (int ni = 0; ni < 4; ++ni) {
        int r0 = m0 + wr * 64 + mi * 16 + quad * 4;
        int b = r0 >> 11, l0 = r0 & 2047;
        int cc = n0 + wc * 64 + ni * 16 + li;
        ushort4 o;
        o.x = f2bf(acc[mi][ni][0]); o.y = f2bf(acc[mi][ni][1]);
        o.z = f2bf(acc[mi][ni][2]); o.w = f2bf(acc[mi][ni][3]);
        *(ushort4*)(vtb + ((size_t)(b * 1024 + cc)) * Ll + l0) = o;
      }
  } else if (t < 640) {  // q: 16 m x 8 n
    int f = t - 512;
    int a = f & 7, n = (f >> 3) & 7, c = f >> 6;  // c in 0..1
    int m0 = (2 * a + c) * 128, n0 = n * 128;
    gemm_pipe<1>(Vin, WqT, m0, n0, As, Bs, acc);
#pragma unroll
    for (int mi = 0; mi < 4; ++mi)
#pragma unroll
      for (int ni = 0; ni < 4; ++ni)
#pragma unroll
        for (int reg = 0; reg < 4; ++reg) {
          int rrow = m0 + wr * 64 + mi * 16 + quad * 4 + reg;
          int cc = n0 + wc * 64 + ni * 16 + li;
          qb[(size_t)rrow * 1024 + cc] = f2bf(acc[mi][ni][reg]);
        }
  } else {  // rk: 24 m x 8 n
    int f = t - 640;
    int a = f & 7, n = (f >> 3) & 7, c = f >> 6;  // c in 0..2
    int m0 = (3 * a + c) * 128, n0 = n * 128;
    gemm_pipe<0>(Pb, WrT, m0, n0, As, Bs, acc);
#pragma unroll
    for (int mi = 0; mi < 4; ++mi)
#pragma unroll
      for (int ni = 0; ni < 4; ++ni)
#pragma unroll
        for (int reg = 0; reg < 4; ++reg) {
          int rrow = m0 + wr * 64 + mi * 16 + quad * 4 + reg;
          int cc = n0 + wc * 64 + ni * 16 + li;
          rkb[(size_t)rrow * 1024 + cc] = f2bf(acc[mi][ni][reg]);
        }
  }
}

// output projection
// R16 (kept): 64x64 tile, grid (32,16) = 512 blocks = 2 blocks/CU so one
// block's DMA drains under the other's MFMA. 16KB LDS, acc[2][2].
__global__ __launch_bounds__(256) void k_gemm_out64(
    const unsigned short* __restrict__ attnb, const unsigned short* __restrict__ WoT,
    float* __restrict__ out) {
  __shared__ unsigned short As[2 * 64 * 32];
  __shared__ unsigned short Bs[2 * 64 * 32];
  int m0 = blockIdx.x * 64, n0 = blockIdx.y * 64;
  const int tid = threadIdx.x, w = tid >> 6, lane = tid & 63;
  const int quad = lane >> 4, li = lane & 15, wr = w >> 1, wc = w & 1;
  f32x4 z = {0.f, 0.f, 0.f, 0.f};
  f32x4 acc[2][2];
#pragma unroll
  for (int mi = 0; mi < 2; ++mi)
#pragma unroll
    for (int ni = 0; ni < 2; ++ni) acc[mi][ni] = z;
  const int rs = lane >> 2, cs = lane & 3;

  {
    int r = w * 16 + rs;
    int c = cs ^ ((r >> 1) & 3);
    gl2lds16(attnb + (size_t)(m0 + r) * 1024 + c * 8, (char*)As + w * 1024);
    gl2lds16(WoT + (size_t)(n0 + r) * 1024 + c * 8, (char*)Bs + w * 1024);
  }

  for (int k0 = 0; k0 < 1024; k0 += 32) {
    const int bo = ((k0 >> 5) & 1) * 4096;
    __builtin_amdgcn_s_waitcnt(0x0F70);
    __syncthreads();
    if (k0 + 32 < 1024) {
      int r = w * 16 + rs;
      int c = cs ^ ((r >> 1) & 3);
      gl2lds16(attnb + (size_t)(m0 + r) * 1024 + k0 + 32 + c * 8,
               (char*)As + (bo ^ 4096) + w * 1024);
      gl2lds16(WoT + (size_t)(n0 + r) * 1024 + k0 + 32 + c * 8,
               (char*)Bs + (bo ^ 4096) + w * 1024);
    }
    bf16x8 af[2], bfr[2];
#pragma unroll
    for (int mi = 0; mi < 2; ++mi) {
      int r = wr * 32 + mi * 16 + li;
      int ch = quad ^ ((r >> 1) & 3);
      af[mi] = *(const bf16x8*)((const char*)As + bo + r * 64 + ch * 16);
    }
#pragma unroll
    for (int ni = 0; ni < 2; ++ni) {
      int r = wc * 32 + ni * 16 + li;
      int ch = quad ^ ((r >> 1) & 3);
      bfr[ni] = *(const bf16x8*)((const char*)Bs + bo + r * 64 + ch * 16);
    }
#pragma unroll
    for (int mi = 0; mi < 2; ++mi)
#pragma unroll
      for (int ni = 0; ni < 2; ++ni)
        acc[mi][ni] = __builtin_amdgcn_mfma_f32_16x16x32_bf16(
            af[mi], bfr[ni], acc[mi][ni], 0, 0, 0);
  }
#pragma unroll
  for (int mi = 0; mi < 2; ++mi)
#pragma unroll
    for (int ni = 0; ni < 2; ++ni)
#pragma unroll
      for (int reg = 0; reg < 4; ++reg) {
        int rrow = m0 + wr * 32 + mi * 16 + quad * 4 + reg;
        int cc = n0 + wc * 32 + ni * 16 + li;
        out[(size_t)rrow * 1024 + cc] = acc[mi][ni][reg];
      }
}

// ---------------- flash attention (R15 best: 77.4us, untouched) -------------
__global__ __launch_bounds__(512, 4) void k_attn(
    const unsigned short* __restrict__ qb, const float* __restrict__ rwb,
    const float* __restrict__ rrb,
    const unsigned short* __restrict__ kb, const unsigned short* __restrict__ vt,
    const unsigned short* __restrict__ rkb, const float* __restrict__ maskf,
    unsigned short* __restrict__ attnb) {
  // LDS map (bytes):
  //   [0,16384)      KS: grp*8192 + buf*4096   (32 j-rows x 64 k, swizzled)
  //   [16384,32768)  VS: grp*8192 + buf*4096   (64 dv-rows x 32 j, swizzled)
  //   [32768,65536)  RS: grp*16384             (128-row ring x 64 k, swizzled)
  //   [65536,75776)  Sb: warp*1280             (16 x 40 half, stride 40)
  //   red = [32768, 53248) reused for cross-group reduction (RS dead by then)
  __shared__ __align__(16) uint8_t lds[75776];

  const int tid = threadIdx.x;
  const int w = tid >> 6, lane = tid & 63;
  const int quad = lane >> 4, li = lane & 15;
  const int wq = w & 3, grp = w >> 2;
  const int srow = lane >> 3, scs = lane & 7;
  // XCD-aware regroup (bijective): 16 qt-blocks of one (b,h) -> one XCD.
  const int flat = blockIdx.x + 16 * blockIdx.y + 256 * blockIdx.z;
  const int qt = (flat >> 3) & 15;
  const int g = 4 * (flat & 7) + (flat >> 7);
  const int h = g & 15, b = g >> 4;
  const int t0blk = qt * 64;
  const int t0w = t0blk + wq * 16;
  const int rboff = 48 - 16 * wq;
  const int rbase0 = Tq - t0blk - 63;
  const int jbase = grp * 1024;

  unsigned short* KS = (unsigned short*)(lds + grp * 8192);
  unsigned short* VS = (unsigned short*)(lds + 16384 + grp * 8192);
  unsigned short* RS = (unsigned short*)(lds + 32768 + grp * 16384);
  unsigned short* pw = (unsigned short*)(lds + 65536 + w * 1280);
  float* red = (float*)(lds + 32768);

  const unsigned short* kbase = kb + ((size_t)(b * Ll + jbase) * Hh + h) * 64;
  const unsigned short* vbase = vt + ((size_t)((b * Hh + h) * 64)) * Ll + jbase;
  const unsigned short* rkbase = rkb + (size_t)h * 64;
  const float* mrowf = maskf + ((size_t)(b * Tq + t0w + li)) * Ll + jbase;

  // q + bias fragments (both groups load the same rows; redundant but cheap)
  bf16x8 aqw[2], aqr[2];
  {
    const unsigned short* p1 = qb + ((size_t)((b * Tq + t0w + li) * Hh + h)) * 64;
#pragma unroll
    for (int ks = 0; ks < 2; ++ks) {
      bf16x8 qf = *(const bf16x8*)(p1 + ks * 32 + quad * 8);
      const float* wp = rwb + h * 64 + ks * 32 + quad * 8;
      const float* rp = rrb + h * 64 + ks * 32 + quad * 8;
      float4 w0 = *(const float4*)wp, w1 = *(const float4*)(wp + 4);
      float4 r0 = *(const float4*)rp, r1 = *(const float4*)(rp + 4);
      float wv[8] = {w0.x, w0.y, w0.z, w0.w, w1.x, w1.y, w1.z, w1.w};
      float rv[8] = {r0.x, r0.y, r0.z, r0.w, r1.x, r1.y, r1.z, r1.w};
#pragma unroll
      for (int i2 = 0; i2 < 8; ++i2) {
        float qv = b2f((unsigned short)qf[i2]);
        aqw[ks][i2] = (short)f2bf(qv + wv[i2]);
        aqr[ks][i2] = (short)f2bf(qv + rv[i2]);
      }
    }
  }

  f32x4 z = {0.f, 0.f, 0.f, 0.f};
  f32x4 o[4];
  o[0] = z; o[1] = z; o[2] = z; o[3] = z;
  f32x4 ol = z;
  float nmf[8] = {0.f, 0.f, 0.f, 0.f, 0.f, 0.f, 0.f, 0.f};

  const float SC = 0.125f * 1.4426950408889634f;
  const float BIGM = 1.442695e30f;
  const short oneb = 0x3F80;
  const bf16x8 onesf = {oneb, oneb, oneb, oneb, oneb, oneb, oneb, oneb};

  int srcl[4];
#pragma unroll
  for (int reg = 0; reg < 4; ++reg) {
    int row = quad * 4 + reg;
    srcl[reg] = (lane & 48) + ((li + row + 1) & 15);
  }

  // finish tile whose S sits in pw: S->P (exp + mask), ol + PV MFMA cluster.
  auto finish = [&](const unsigned short* VsP, const float (&mv)[8]) {
    bf16x8 sv = *(const bf16x8*)(pw + li * 40 + quad * 8);
    float p[8];
#pragma unroll
    for (int i2 = 0; i2 < 8; ++i2) {
      float sf = __half2float(__builtin_bit_cast(__half, (unsigned short)sv[i2]));
      float mvneg = fmaf(mv[i2], BIGM, -BIGM);  // -(1-m)*BIGM
      p[i2] = exp2f(fmaf(sf, SC, mvneg));
    }
    int4 pk;
    pk.x = (int)cvt_pk_bf16(p[0], p[1]);
    pk.y = (int)cvt_pk_bf16(p[2], p[3]);
    pk.z = (int)cvt_pk_bf16(p[4], p[5]);
    pk.w = (int)cvt_pk_bf16(p[6], p[7]);
    bf16x8 apv = __builtin_bit_cast(bf16x8, pk);
    __builtin_amdgcn_s_setprio(1);
    ol = __builtin_amdgcn_mfma_f32_16x16x32_bf16(apv, onesf, ol, 0, 0, 0);
#pragma unroll
    for (int nt = 0; nt < 4; ++nt) {
      int dv = nt * 16 + li;
      int ch = quad ^ ((dv >> 1) & 3);  // V-fix: perm=(dv>>1)&3
      bf16x8 vf = *(const bf16x8*)(VsP + dv * 32 + ch * 8);
      o[nt] = __builtin_amdgcn_mfma_f32_16x16x32_bf16(apv, vf, o[nt], 0, 0, 0);
    }
    __builtin_amdgcn_s_setprio(0);
  };

  // prologue: R ring rows u in [0,96); K[0]. V is lag-1 (loaded in-loop).
#pragma unroll
  for (int pass = 0; pass < 3; ++pass) {
    int u = pass * 32 + wq * 8 + srow;
    int gr = rbase0 + jbase + u;
    if (gr > Rr - 1) gr = Rr - 1;
    int c = scs ^ srow;
    gl2lds16(rkbase + (size_t)gr * 1024 + c * 8, RS + (pass * 32 + wq * 8) * 64);
  }
  {
    int r = wq * 8 + srow;
    int c = scs ^ srow;
    gl2lds16(kbase + (size_t)r * 1024 + c * 8, KS + wq * 512);
  }

  for (int jt = 0; jt < 32; ++jt) {
    const int jloc = jt * 32;
    __builtin_amdgcn_s_waitcnt(0x0F70);  // vmcnt(0)
    __syncthreads();
    // ---- prefetch: K[jt+1], R[jloc+96,+128) (jt<31); V[jt] (always) ----
    if (jt < 31) {
      {
        int r = wq * 8 + srow;
        int c = scs ^ srow;
        gl2lds16(kbase + (size_t)(jloc + 32 + r) * 1024 + c * 8,
                 KS + (((jt + 1) & 1) * 2048) + wq * 512);
      }
      {
        int u = jloc + 96 + wq * 8 + srow;
        int gr = rbase0 + jbase + u;
        if (gr > Rr - 1) gr = Rr - 1;
        int c = scs ^ srow;
        gl2lds16(rkbase + (size_t)gr * 1024 + c * 8,
                 RS + ((jloc + 96 + wq * 8) & 127) * 64);
      }
    }
    {
      int dv = wq * 16 + (lane >> 2);
      int c = (lane & 3) ^ ((dv >> 1) & 3);  // V-fix: perm=(dv>>1)&3
      gl2lds16(vbase + (size_t)dv * Ll + jloc + c * 8,
               VS + ((jt & 1) * 2048) + wq * 512);
    }
    asm volatile("" ::: "memory");
    // ---- QK^T + rel for tile jt (covers pw write->read turnaround) ----
    const unsigned short* KsC = KS + (jt & 1) * 2048;
    f32x4 sc[2];
    sc[0] = z; sc[1] = z;
    __builtin_amdgcn_s_setprio(1);
#pragma unroll
    for (int ks = 0; ks < 2; ++ks)
#pragma unroll
      for (int nt = 0; nt < 2; ++nt) {
        int j = nt * 16 + li;
        int ch = (ks * 4 + quad) ^ (j & 7);
        bf16x8 kf = *(const bf16x8*)(KsC + j * 64 + ch * 8);
        sc[nt] = __builtin_amdgcn_mfma_f32_16x16x32_bf16(aqw[ks], kf, sc[nt], 0, 0, 0);
      }
    f32x4 bd[3];
    bd[0] = z; bd[1] = z; bd[2] = z;
#pragma unroll
    for (int ks = 0; ks < 2; ++ks)
#pragma unroll
      for (int nt = 0; nt < 3; ++nt) {
        int pr = (rboff + nt * 16 + li + jloc) & 127;
        int ch = (ks * 4 + quad) ^ (pr & 7);
        bf16x8 rf = *(const bf16x8*)(RS + pr * 64 + ch * 8);
        bd[nt] = __builtin_amdgcn_mfma_f32_16x16x32_bf16(aqr[ks], rf, bd[nt], 0, 0, 0);
      }
    __builtin_amdgcn_s_setprio(0);
    // ---- finish tile jt-1 (S read from pw, written a full iter ago) ----
    if (jt > 0) finish(VS + ((jt - 1) & 1) * 2048, nmf);
    // mask (f32) for tile jt: raw loads register-lagged, consumed at finish
    // in jt+1 (full-iteration latency cover, WAR-safe)
    {
      float4 m0 = *(const float4*)(mrowf + jloc + quad * 8);
      float4 m1 = *(const float4*)(mrowf + jloc + quad * 8 + 4);
      nmf[0] = m0.x; nmf[1] = m0.y; nmf[2] = m0.z; nmf[3] = m0.w;
      nmf[4] = m1.x; nmf[5] = m1.y; nmf[6] = m1.z; nmf[7] = m1.w;
    }
    // ---- rel-shift combine + write S(jt) into pw ----
    float rot[2][4];
#pragma unroll
    for (int nt = 0; nt < 2; ++nt)
#pragma unroll
      for (int reg = 0; reg < 4; ++reg)
        rot[nt][reg] = __shfl(sc[nt][reg], srcl[reg], 64);
#pragma unroll
    for (int nt = 0; nt < 3; ++nt)
#pragma unroll
      for (int reg = 0; reg < 4; ++reg) {
        int row = quad * 4 + reg;
        int jj = nt * 16 + li + row - 15;
        int nthi = (nt > 1) ? 0 : nt;
        int ntlo = (nt == 0) ? 0 : (nt - 1);
        float val = ((li + row) >= 15) ? rot[nthi][reg] : rot[ntlo][reg];
        float s = val + bd[nt][reg];
        if ((unsigned)jj < 32u)
          pw[row * 40 + jj] = __builtin_bit_cast(unsigned short, __float2half(s));
      }
  }
  // epilogue: drain V[31]+mask, finish tile 31
  __builtin_amdgcn_s_waitcnt(0x0F70);
  __syncthreads();
  finish(VS + 2048, nmf);

  // ---- cross-group reduction (red overlays RS region; RS dead) ----
  if (grp == 1) {
    float* rp = red + (size_t)(wq * 64 + lane) * 20;
#pragma unroll
    for (int nt = 0; nt < 4; ++nt)
#pragma unroll
      for (int reg = 0; reg < 4; ++reg) rp[nt * 4 + reg] = o[nt][reg];
#pragma unroll
    for (int reg = 0; reg < 4; ++reg) rp[16 + reg] = ol[reg];
  }
  __syncthreads();
  if (grp == 0) {
    const float* rp = red + (size_t)(wq * 64 + lane) * 20;
    float inv[4];
#pragma unroll
    for (int reg = 0; reg < 4; ++reg) inv[reg] = 1.0f / (ol[reg] + rp[16 + reg]);
#pragma unroll
    for (int nt = 0; nt < 4; ++nt)
#pragma unroll
      for (int reg = 0; reg < 4; ++reg) {
        int trow = t0w + quad * 4 + reg;
        float val = (o[nt][reg] + rp[nt * 4 + reg]) * inv[reg];
        attnb[((size_t)(b * Tq + trow)) * 1024 + h * 64 + nt * 16 + li] = f2bf(val);
      }
  }
}

extern "C" void kernel_launch(void* const* d_in, const int* in_sizes, int n_in,
                              void* d_out, int out_size, void* d_ws, size_t ws_size,
                              hipStream_t stream) {
  const float* x = (const float*)d_in[0];
  const float* mask = (const float*)d_in[1];
  const float* pos = (const float*)d_in[2];
  const float* mem = (const float*)d_in[3];
  const float* Wq = (const float*)d_in[4];
  const float* Wk = (const float*)d_in[5];
  const float* Wv = (const float*)d_in[6];
  const float* Wr = (const float*)d_in[7];
  const float* rwb = (const float*)d_in[8];
  const float* rrb = (const float*)d_in[9];
  const float* Wo = (const float*)d_in[10];
  float* out = (float*)d_out;

  uint8_t* ws = (uint8_t*)d_ws;
  const size_t MB = 1024 * 1024;
  unsigned short* Vinb = (unsigned short*)(ws + 0);
  unsigned short* WqT = (unsigned short*)(ws + 8 * MB);
  unsigned short* WkT = (unsigned short*)(ws + 10 * MB);
  unsigned short* WvT = (unsigned short*)(ws + 12 * MB);
  unsigned short* WrT = (unsigned short*)(ws + 14 * MB);
  unsigned short* WoT = (unsigned short*)(ws + 16 * MB);
  unsigned short* Pb = (unsigned short*)(ws + 18 * MB);
  unsigned short* qb = (unsigned short*)(ws + 24 * MB);
  unsigned short* kb = (unsigned short*)(ws + 32 * MB);
  unsigned short* vtb = (unsigned short*)(ws + 40 * MB);
  unsigned short* rkb = (unsigned short*)(ws + 48 * MB);
  unsigned short* attnb = (unsigned short*)(ws + 19 * MB);

  hipLaunchKernelGGL(k_prep2, dim3(8448), dim3(256), 0, stream,
                     x, mem, pos, Wq, Wk, Wv, Wr, Wo,
                     Vinb, Pb, WqT, WkT, WvT, WrT, WoT);
  hipLaunchKernelGGL(k_proj, dim3(832), dim3(256), 0, stream,
                     Vinb, Pb, WqT, WkT, WvT, WrT, qb, kb, vtb, rkb);
  hipLaunchKernelGGL(k_attn, dim3(16, 16, 2), dim3(512), 0, stream,
                     qb, rwb, rrb, kb, vtb, rkb, mask, attnb);
  hipLaunchKernelGGL(k_gemm_out64, dim3(32, 16), dim3(256), 0, stream,
                     attnb, WoT, out);
}

// Round 11
// 234.328 us; speedup vs baseline: 1.1461x; 1.0229x over previous
//
#include <hip/hip_runtime.h>
#include <hip/hip_fp16.h>
#include <stdint.h>

#define Bz 2
#define Tq 1024
#define Mm 1024
#define Hh 16
#define Ll 2048
#define Rr 3072

typedef __attribute__((ext_vector_type(8))) short bf16x8;
typedef __attribute__((ext_vector_type(4))) float f32x4;

typedef __attribute__((address_space(3))) uint8_t lds_u8_t;
typedef __attribute__((address_space(1))) uint8_t glb_u8_t;

__device__ __forceinline__ void gl2lds16(const void* g, void* l) {
  __builtin_amdgcn_global_load_lds((const glb_u8_t*)g, (lds_u8_t*)l, 16, 0, 0);
}

__device__ __forceinline__ unsigned short f2bf(float f) {
  unsigned int u = __builtin_bit_cast(unsigned int, f);
  u = u + 0x7fffu + ((u >> 16) & 1u);
  return (unsigned short)(u >> 16);
}
__device__ __forceinline__ float b2f(unsigned short s) {
  unsigned int u = ((unsigned int)s) << 16;
  return __builtin_bit_cast(float, u);
}
// packed f32x2 -> bf16x2 (RNE), gfx950; no builtin exists (T12/m240)
__device__ __forceinline__ unsigned int cvt_pk_bf16(float lo, float hi) {
  unsigned int r;
  asm volatile("v_cvt_pk_bf16_f32 %0, %1, %2" : "=v"(r) : "v"(lo), "v"(hi));
  return r;
}

// ------- prep (merged): values cast | pos cast | 5x W transpose -------------
__global__ __launch_bounds__(256) void k_prep2(
    const float* __restrict__ x, const float* __restrict__ mem,
    const float* __restrict__ pos,
    const float* __restrict__ w0, const float* __restrict__ w1,
    const float* __restrict__ w2, const float* __restrict__ w3,
    const float* __restrict__ w4,
    unsigned short* __restrict__ vin, unsigned short* __restrict__ pb,
    unsigned short* __restrict__ t0, unsigned short* __restrict__ t1,
    unsigned short* __restrict__ t2, unsigned short* __restrict__ t3,
    unsigned short* __restrict__ t4) {
  __shared__ float tile[64][65];
  int bid = blockIdx.x;
  if (bid < 4096) {
    int idx = bid * 256 + threadIdx.x;
    int e = idx << 2;
    int row = e >> 10, col = e & 1023;
    int b = row >> 11, l = row & 2047;
    const float* s = (l < Mm) ? (mem + (((size_t)b * Mm + l) << 10) + col)
                              : (x + (((size_t)b * Tq + (l - Mm)) << 10) + col);
    float4 v = *(const float4*)s;
    ushort4 o;
    o.x = f2bf(v.x); o.y = f2bf(v.y); o.z = f2bf(v.z); o.w = f2bf(v.w);
    *(ushort4*)(vin + e) = o;
  } else if (bid < 7168) {
    int idx = (bid - 4096) * 256 + threadIdx.x;
    int e = idx << 2;
    float4 v = *(const float4*)(pos + e);
    ushort4 t;
    t.x = f2bf(v.x); t.y = f2bf(v.y); t.z = f2bf(v.z); t.w = f2bf(v.w);
    *(ushort4*)(pb + e) = t;
  } else {
    int r3 = bid - 7168;
    int mz = r3 >> 8, rem = r3 & 255;
    const float* W;
    unsigned short* WT;
    switch (mz) {
      case 0: W = w0; WT = t0; break;
      case 1: W = w1; WT = t1; break;
      case 2: W = w2; WT = t2; break;
      case 3: W = w3; WT = t3; break;
      default: W = w4; WT = t4; break;
    }
    int k0 = (rem >> 4) * 64, n0 = (rem & 15) * 64;
    int tid = threadIdx.x;
    int rr = tid >> 4, c4 = (tid & 15) * 4;
#pragma unroll
    for (int it = 0; it < 4; ++it) {
      int r = rr + it * 16;
      float4 v = *(const float4*)(W + (size_t)(k0 + r) * 1024 + n0 + c4);
      tile[r][c4] = v.x; tile[r][c4 + 1] = v.y;
      tile[r][c4 + 2] = v.z; tile[r][c4 + 3] = v.w;
    }
    __syncthreads();
#pragma unroll
    for (int it = 0; it < 4; ++it) {
      int n = rr + it * 16;
      ushort4 o;
      o.x = f2bf(tile[c4 + 0][n]); o.y = f2bf(tile[c4 + 1][n]);
      o.z = f2bf(tile[c4 + 2][n]); o.w = f2bf(tile[c4 + 3][n]);
      *(ushort4*)(WT + (size_t)(n0 + n) * 1024 + k0 + c4) = o;
    }
  }
}

// ------- bf16 NT GEMM core, single-barrier pipelined, dbuf LDS (K=1024) -----
template <int RMAP>
__device__ __forceinline__ void gemm_pipe(const unsigned short* __restrict__ A,
                                          const unsigned short* __restrict__ Bt,
                                          int m0, int n0, unsigned short* As,
                                          unsigned short* Bs, f32x4 acc[4][4]) {
  const int tid = threadIdx.x;
  const int w = tid >> 6, lane = tid & 63;
  const int quad = lane >> 4, li = lane & 15;
  const int wr = w >> 1, wc = w & 1;
  f32x4 z = {0.f, 0.f, 0.f, 0.f};
#pragma unroll
  for (int mi = 0; mi < 4; ++mi)
#pragma unroll
    for (int ni = 0; ni < 4; ++ni) acc[mi][ni] = z;

  const int rs = lane >> 2;
  const int cs = lane & 3;

#pragma unroll
  for (int s = 0; s < 2; ++s) {
    int i = w * 2 + s;
    int r = i * 16 + rs;
    int c = cs ^ ((r >> 1) & 3);
    int ar = m0 + r;
    if (RMAP) ar = ar + 1024 + (ar & 1024);
    gl2lds16(A + (size_t)ar * 1024 + c * 8, (char*)As + i * 1024);
    gl2lds16(Bt + (size_t)(n0 + r) * 1024 + c * 8, (char*)Bs + i * 1024);
  }

  for (int k0 = 0; k0 < 1024; k0 += 32) {
    const int bo = ((k0 >> 5) & 1) * 8192;
    const int no = bo ^ 8192;
    __builtin_amdgcn_s_waitcnt(0x0F70);
    __syncthreads();
    if (k0 + 32 < 1024) {
#pragma unroll
      for (int s = 0; s < 2; ++s) {
        int i = w * 2 + s;
        int r = i * 16 + rs;
        int c = cs ^ ((r >> 1) & 3);
        int ar = m0 + r;
        if (RMAP) ar = ar + 1024 + (ar & 1024);
        gl2lds16(A + (size_t)ar * 1024 + k0 + 32 + c * 8,
                 (char*)As + no + i * 1024);
        gl2lds16(Bt + (size_t)(n0 + r) * 1024 + k0 + 32 + c * 8,
                 (char*)Bs + no + i * 1024);
      }
    }
    bf16x8 af[4], bfr[4];
#pragma unroll
    for (int mi = 0; mi < 4; ++mi) {
      int r = wr * 64 + mi * 16 + li;
      int ch = quad ^ ((r >> 1) & 3);
      af[mi] = *(const bf16x8*)((const char*)As + bo + r * 64 + ch * 16);
    }
#pragma unroll
    for (int ni = 0; ni < 4; ++ni) {
      int r = wc * 64 + ni * 16 + li;
      int ch = quad ^ ((r >> 1) & 3);
      bfr[ni] = *(const bf16x8*)((const char*)Bs + bo + r * 64 + ch * 16);
    }
#pragma unroll
    for (int mi = 0; mi < 4; ++mi)
#pragma unroll
      for (int ni = 0; ni < 4; ++ni)
        acc[mi][ni] = __builtin_amdgcn_mfma_f32_16x16x32_bf16(
            af[mi], bfr[ni], acc[mi][ni], 0, 0, 0);
  }
}

// fused projections (R17: XCD regroup per segment; R7 scatter v-store)
__global__ __launch_bounds__(256) void k_proj(
    const unsigned short* __restrict__ Vin, const unsigned short* __restrict__ Pb,
    const unsigned short* __restrict__ WqT, const unsigned short* __restrict__ WkT,
    const unsigned short* __restrict__ WvT, const unsigned short* __restrict__ WrT,
    unsigned short* __restrict__ qb, unsigned short* __restrict__ kb,
    unsigned short* __restrict__ vtb, unsigned short* __restrict__ rkb) {
  __shared__ unsigned short As[2 * 128 * 32];
  __shared__ unsigned short Bs[2 * 128 * 32];
  const int t = blockIdx.x;
  const int tid = threadIdx.x, w = tid >> 6, lane = tid & 63;
  const int quad = lane >> 4, li = lane & 15, wr = w >> 1, wc = w & 1;
  f32x4 acc[4][4];

  if (t < 256) {  // k: 32 m-tiles x 8 n-tiles
    int a = t & 7, n = (t >> 3) & 7, c = t >> 6;
    int m0 = (4 * a + c) * 128, n0 = n * 128;
    gemm_pipe<0>(Vin, WkT, m0, n0, As, Bs, acc);
#pragma unroll
    for (int mi = 0; mi < 4; ++mi)
#pragma unroll
      for (int ni = 0; ni < 4; ++ni)
#pragma unroll
        for (int reg = 0; reg < 4; ++reg) {
          int rrow = m0 + wr * 64 + mi * 16 + quad * 4 + reg;
          int cc = n0 + wc * 64 + ni * 16 + li;
          kb[(size_t)rrow * 1024 + cc] = f2bf(acc[mi][ni][reg]);
        }
  } else if (t < 512) {  // v: 32 m x 8 n, R7 scatter store
    int f = t - 256;
    int a = f & 7, n = (f >> 3) & 7, c = f >> 6;
    int m0 = (4 * a + c) * 128, n0 = n * 128;
    gemm_pipe<0>(Vin, WvT, m0, n0, As, Bs, acc);
#pragma unroll
    for (int mi = 0; mi < 4; ++mi)
#pragma unroll
      for (int ni = 0; ni < 4; ++ni) {
        int r0 = m0 + wr * 64 + mi * 16 + quad * 4;
        int b = r0 >> 11, l0 = r0 & 2047;
        int cc = n0 + wc * 64 + ni * 16 + li;
        ushort4 o;
        o.x = f2bf(acc[mi][ni][0]); o.y = f2bf(acc[mi][ni][1]);
        o.z = f2bf(acc[mi][ni][2]); o.w = f2bf(acc[mi][ni][3]);
        *(ushort4*)(vtb + ((size_t)(b * 1024 + cc)) * Ll + l0) = o;
      }
  } else if (t < 640) {  // q: 16 m x 8 n
    int f = t - 512;
    int a = f & 7, n = (f >> 3) & 7, c = f >> 6;  // c in 0..1
    int m0 = (2 * a + c) * 128, n0 = n * 128;
    gemm_pipe<1>(Vin, WqT, m0, n0, As, Bs, acc);
#pragma unroll
    for (int mi = 0; mi < 4; ++mi)
#pragma unroll
      for (int ni = 0; ni < 4; ++ni)
#pragma unroll
        for (int reg = 0; reg < 4; ++reg) {
          int rrow = m0 + wr * 64 + mi * 16 + quad * 4 + reg;
          int cc = n0 + wc * 64 + ni * 16 + li;
          qb[(size_t)rrow * 1024 + cc] = f2bf(acc[mi][ni][reg]);
        }
  } else {  // rk: 24 m x 8 n
    int f = t - 640;
    int a = f & 7, n = (f >> 3) & 7, c = f >> 6;  // c in 0..2
    int m0 = (3 * a + c) * 128, n0 = n * 128;
    gemm_pipe<0>(Pb, WrT, m0, n0, As, Bs, acc);
#pragma unroll
    for (int mi = 0; mi < 4; ++mi)
#pragma unroll
      for (int ni = 0; ni < 4; ++ni)
#pragma unroll
        for (int reg = 0; reg < 4; ++reg) {
          int rrow = m0 + wr * 64 + mi * 16 + quad * 4 + reg;
          int cc = n0 + wc * 64 + ni * 16 + li;
          rkb[(size_t)rrow * 1024 + cc] = f2bf(acc[mi][ni][reg]);
        }
  }
}

// output projection
// R19 = R18 with the s_waitcnt literal-constant fix (builtin requires an
// immediate; wave-uniform branch selects between two constant-arg calls).
// 64x64 tile + 3-deep counted-vmcnt pipeline: loads for step it issued at
// it-2 stay in flight across TWO raw s_barriers; loop-top wait is
// vmcnt(2)+lgkm(0) (never vmcnt(0) in main loop, T4). WAR-safe: issue at
// iter it targets buf((it+2)%3)=buf((it-1)%3) whose readers all passed
// this iter's barrier.
__global__ __launch_bounds__(256) void k_gemm_out64(
    const unsigned short* __restrict__ attnb, const unsigned short* __restrict__ WoT,
    float* __restrict__ out) {
  __shared__ unsigned short As[3 * 64 * 32];
  __shared__ unsigned short Bs[3 * 64 * 32];
  int m0 = blockIdx.x * 64, n0 = blockIdx.y * 64;
  const int tid = threadIdx.x, w = tid >> 6, lane = tid & 63;
  const int quad = lane >> 4, li = lane & 15, wr = w >> 1, wc = w & 1;
  f32x4 z = {0.f, 0.f, 0.f, 0.f};
  f32x4 acc[2][2];
#pragma unroll
  for (int mi = 0; mi < 2; ++mi)
#pragma unroll
    for (int ni = 0; ni < 2; ++ni) acc[mi][ni] = z;
  const int rs = lane >> 2, cs = lane & 3;
  const int r = w * 16 + rs;
  const int c = cs ^ ((r >> 1) & 3);
  const unsigned short* aRow = attnb + (size_t)(m0 + r) * 1024 + c * 8;
  const unsigned short* bRow = WoT + (size_t)(n0 + r) * 1024 + c * 8;

  // prologue: issue k-steps 0 and 1 into bufs 0,1 (2 VMEM ops per step/warp)
  gl2lds16(aRow, (char*)As + w * 1024);
  gl2lds16(bRow, (char*)Bs + w * 1024);
  gl2lds16(aRow + 32, (char*)As + 4096 + w * 1024);
  gl2lds16(bRow + 32, (char*)Bs + 4096 + w * 1024);

  for (int it = 0; it < 32; ++it) {
    const int bo = (it % 3) * 4096;
    // drain THIS buf's loads only; own LDS ops done (protects buf about to
    // be overwritten). vmcnt(2)|lgkmcnt(0) in steady state; full drain last.
    if (it < 31)
      __builtin_amdgcn_s_waitcnt(0x0072);  // vmcnt(2) lgkmcnt(0)
    else
      __builtin_amdgcn_s_waitcnt(0x0070);  // vmcnt(0) lgkmcnt(0)
    __builtin_amdgcn_s_barrier();
    if (it + 2 < 32) {
      const int nb = ((it + 2) % 3) * 4096;
      const int k2 = (it + 2) * 32;
      gl2lds16(aRow + k2, (char*)As + nb + w * 1024);
      gl2lds16(bRow + k2, (char*)Bs + nb + w * 1024);
    }
    asm volatile("" ::: "memory");
    bf16x8 af[2], bfr[2];
#pragma unroll
    for (int mi = 0; mi < 2; ++mi) {
      int rr = wr * 32 + mi * 16 + li;
      int ch = quad ^ ((rr >> 1) & 3);
      af[mi] = *(const bf16x8*)((const char*)As + bo + rr * 64 + ch * 16);
    }
#pragma unroll
    for (int ni = 0; ni < 2; ++ni) {
      int rr = wc * 32 + ni * 16 + li;
      int ch = quad ^ ((rr >> 1) & 3);
      bfr[ni] = *(const bf16x8*)((const char*)Bs + bo + rr * 64 + ch * 16);
    }
#pragma unroll
    for (int mi = 0; mi < 2; ++mi)
#pragma unroll
      for (int ni = 0; ni < 2; ++ni)
        acc[mi][ni] = __builtin_amdgcn_mfma_f32_16x16x32_bf16(
            af[mi], bfr[ni], acc[mi][ni], 0, 0, 0);
  }
#pragma unroll
  for (int mi = 0; mi < 2; ++mi)
#pragma unroll
    for (int ni = 0; ni < 2; ++ni)
#pragma unroll
      for (int reg = 0; reg < 4; ++reg) {
        int rrow = m0 + wr * 32 + mi * 16 + quad * 4 + reg;
        int cc = n0 + wc * 32 + ni * 16 + li;
        out[(size_t)rrow * 1024 + cc] = acc[mi][ni][reg];
      }
}

// ---------------- flash attention (R15 best: 77.4us, untouched) -------------
__global__ __launch_bounds__(512, 4) void k_attn(
    const unsigned short* __restrict__ qb, const float* __restrict__ rwb,
    const float* __restrict__ rrb,
    const unsigned short* __restrict__ kb, const unsigned short* __restrict__ vt,
    const unsigned short* __restrict__ rkb, const float* __restrict__ maskf,
    unsigned short* __restrict__ attnb) {
  // LDS map (bytes):
  //   [0,16384)      KS: grp*8192 + buf*4096   (32 j-rows x 64 k, swizzled)
  //   [16384,32768)  VS: grp*8192 + buf*4096   (64 dv-rows x 32 j, swizzled)
  //   [32768,65536)  RS: grp*16384             (128-row ring x 64 k, swizzled)
  //   [65536,75776)  Sb: warp*1280             (16 x 40 half, stride 40)
  //   red = [32768, 53248) reused for cross-group reduction (RS dead by then)
  __shared__ __align__(16) uint8_t lds[75776];

  const int tid = threadIdx.x;
  const int w = tid >> 6, lane = tid & 63;
  const int quad = lane >> 4, li = lane & 15;
  const int wq = w & 3, grp = w >> 2;
  const int srow = lane >> 3, scs = lane & 7;
  // XCD-aware regroup (bijective): 16 qt-blocks of one (b,h) -> one XCD.
  const int flat = blockIdx.x + 16 * blockIdx.y + 256 * blockIdx.z;
  const int qt = (flat >> 3) & 15;
  const int g = 4 * (flat & 7) + (flat >> 7);
  const int h = g & 15, b = g >> 4;
  const int t0blk = qt * 64;
  const int t0w = t0blk + wq * 16;
  const int rboff = 48 - 16 * wq;
  const int rbase0 = Tq - t0blk - 63;
  const int jbase = grp * 1024;

  unsigned short* KS = (unsigned short*)(lds + grp * 8192);
  unsigned short* VS = (unsigned short*)(lds + 16384 + grp * 8192);
  unsigned short* RS = (unsigned short*)(lds + 32768 + grp * 16384);
  unsigned short* pw = (unsigned short*)(lds + 65536 + w * 1280);
  float* red = (float*)(lds + 32768);

  const unsigned short* kbase = kb + ((size_t)(b * Ll + jbase) * Hh + h) * 64;
  const unsigned short* vbase = vt + ((size_t)((b * Hh + h) * 64)) * Ll + jbase;
  const unsigned short* rkbase = rkb + (size_t)h * 64;
  const float* mrowf = maskf + ((size_t)(b * Tq + t0w + li)) * Ll + jbase;

  // q + bias fragments (both groups load the same rows; redundant but cheap)
  bf16x8 aqw[2], aqr[2];
  {
    const unsigned short* p1 = qb + ((size_t)((b * Tq + t0w + li) * Hh + h)) * 64;
#pragma unroll
    for (int ks = 0; ks < 2; ++ks) {
      bf16x8 qf = *(const bf16x8*)(p1 + ks * 32 + quad * 8);
      const float* wp = rwb + h * 64 + ks * 32 + quad * 8;
      const float* rp = rrb + h * 64 + ks * 32 + quad * 8;
      float4 w0 = *(const float4*)wp, w1 = *(const float4*)(wp + 4);
      float4 r0 = *(const float4*)rp, r1 = *(const float4*)(rp + 4);
      float wv[8] = {w0.x, w0.y, w0.z, w0.w, w1.x, w1.y, w1.z, w1.w};
      float rv[8] = {r0.x, r0.y, r0.z, r0.w, r1.x, r1.y, r1.z, r1.w};
#pragma unroll
      for (int i2 = 0; i2 < 8; ++i2) {
        float qv = b2f((unsigned short)qf[i2]);
        aqw[ks][i2] = (short)f2bf(qv + wv[i2]);
        aqr[ks][i2] = (short)f2bf(qv + rv[i2]);
      }
    }
  }

  f32x4 z = {0.f, 0.f, 0.f, 0.f};
  f32x4 o[4];
  o[0] = z; o[1] = z; o[2] = z; o[3] = z;
  f32x4 ol = z;
  float nmf[8] = {0.f, 0.f, 0.f, 0.f, 0.f, 0.f, 0.f, 0.f};

  const float SC = 0.125f * 1.4426950408889634f;
  const float BIGM = 1.442695e30f;
  const short oneb = 0x3F80;
  const bf16x8 onesf = {oneb, oneb, oneb, oneb, oneb, oneb, oneb, oneb};

  int srcl[4];
#pragma unroll
  for (int reg = 0; reg < 4; ++reg) {
    int row = quad * 4 + reg;
    srcl[reg] = (lane & 48) + ((li + row + 1) & 15);
  }

  // finish tile whose S sits in pw: S->P (exp + mask), ol + PV MFMA cluster.
  auto finish = [&](const unsigned short* VsP, const float (&mv)[8]) {
    bf16x8 sv = *(const bf16x8*)(pw + li * 40 + quad * 8);
    float p[8];
#pragma unroll
    for (int i2 = 0; i2 < 8; ++i2) {
      float sf = __half2float(__builtin_bit_cast(__half, (unsigned short)sv[i2]));
      float mvneg = fmaf(mv[i2], BIGM, -BIGM);  // -(1-m)*BIGM
      p[i2] = exp2f(fmaf(sf, SC, mvneg));
    }
    int4 pk;
    pk.x = (int)cvt_pk_bf16(p[0], p[1]);
    pk.y = (int)cvt_pk_bf16(p[2], p[3]);
    pk.z = (int)cvt_pk_bf16(p[4], p[5]);
    pk.w = (int)cvt_pk_bf16(p[6], p[7]);
    bf16x8 apv = __builtin_bit_cast(bf16x8, pk);
    __builtin_amdgcn_s_setprio(1);
    ol = __builtin_amdgcn_mfma_f32_16x16x32_bf16(apv, onesf, ol, 0, 0, 0);
#pragma unroll
    for (int nt = 0; nt < 4; ++nt) {
      int dv = nt * 16 + li;
      int ch = quad ^ ((dv >> 1) & 3);  // V-fix: perm=(dv>>1)&3
      bf16x8 vf = *(const bf16x8*)(VsP + dv * 32 + ch * 8);
      o[nt] = __builtin_amdgcn_mfma_f32_16x16x32_bf16(apv, vf, o[nt], 0, 0, 0);
    }
    __builtin_amdgcn_s_setprio(0);
  };

  // prologue: R ring rows u in [0,96); K[0]. V is lag-1 (loaded in-loop).
#pragma unroll
  for (int pass = 0; pass < 3; ++pass) {
    int u = pass * 32 + wq * 8 + srow;
    int gr = rbase0 + jbase + u;
    if (gr > Rr - 1) gr = Rr - 1;
    int c = scs ^ srow;
    gl2lds16(rkbase + (size_t)gr * 1024 + c * 8, RS + (pass * 32 + wq * 8) * 64);
  }
  {
    int r = wq * 8 + srow;
    int c = scs ^ srow;
    gl2lds16(kbase + (size_t)r * 1024 + c * 8, KS + wq * 512);
  }

  for (int jt = 0; jt < 32; ++jt) {
    const int jloc = jt * 32;
    __builtin_amdgcn_s_waitcnt(0x0F70);  // vmcnt(0)
    __syncthreads();
    // ---- prefetch: K[jt+1], R[jloc+96,+128) (jt<31); V[jt] (always) ----
    if (jt < 31) {
      {
        int r = wq * 8 + srow;
        int c = scs ^ srow;
        gl2lds16(kbase + (size_t)(jloc + 32 + r) * 1024 + c * 8,
                 KS + (((jt + 1) & 1) * 2048) + wq * 512);
      }
      {
        int u = jloc + 96 + wq * 8 + srow;
        int gr = rbase0 + jbase + u;
        if (gr > Rr - 1) gr = Rr - 1;
        int c = scs ^ srow;
        gl2lds16(rkbase + (size_t)gr * 1024 + c * 8,
                 RS + ((jloc + 96 + wq * 8) & 127) * 64);
      }
    }
    {
      int dv = wq * 16 + (lane >> 2);
      int c = (lane & 3) ^ ((dv >> 1) & 3);  // V-fix: perm=(dv>>1)&3
      gl2lds16(vbase + (size_t)dv * Ll + jloc + c * 8,
               VS + ((jt & 1) * 2048) + wq * 512);
    }
    asm volatile("" ::: "memory");
    // ---- QK^T + rel for tile jt (covers pw write->read turnaround) ----
    const unsigned short* KsC = KS + (jt & 1) * 2048;
    f32x4 sc[2];
    sc[0] = z; sc[1] = z;
    __builtin_amdgcn_s_setprio(1);
#pragma unroll
    for (int ks = 0; ks < 2; ++ks)
#pragma unroll
      for (int nt = 0; nt < 2; ++nt) {
        int j = nt * 16 + li;
        int ch = (ks * 4 + quad) ^ (j & 7);
        bf16x8 kf = *(const bf16x8*)(KsC + j * 64 + ch * 8);
        sc[nt] = __builtin_amdgcn_mfma_f32_16x16x32_bf16(aqw[ks], kf, sc[nt], 0, 0, 0);
      }
    f32x4 bd[3];
    bd[0] = z; bd[1] = z; bd[2] = z;
#pragma unroll
    for (int ks = 0; ks < 2; ++ks)
#pragma unroll
      for (int nt = 0; nt < 3; ++nt) {
        int pr = (rboff + nt * 16 + li + jloc) & 127;
        int ch = (ks * 4 + quad) ^ (pr & 7);
        bf16x8 rf = *(const bf16x8*)(RS + pr * 64 + ch * 8);
        bd[nt] = __builtin_amdgcn_mfma_f32_16x16x32_bf16(aqr[ks], rf, bd[nt], 0, 0, 0);
      }
    __builtin_amdgcn_s_setprio(0);
    // ---- finish tile jt-1 (S read from pw, written a full iter ago) ----
    if (jt > 0) finish(VS + ((jt - 1) & 1) * 2048, nmf);
    // mask (f32) for tile jt: raw loads register-lagged, consumed at finish
    // in jt+1 (full-iteration latency cover, WAR-safe)
    {
      float4 m0 = *(const float4*)(mrowf + jloc + quad * 8);
      float4 m1 = *(const float4*)(mrowf + jloc + quad * 8 + 4);
      nmf[0] = m0.x; nmf[1] = m0.y; nmf[2] = m0.z; nmf[3] = m0.w;
      nmf[4] = m1.x; nmf[5] = m1.y; nmf[6] = m1.z; nmf[7] = m1.w;
    }
    // ---- rel-shift combine + write S(jt) into pw ----
    float rot[2][4];
#pragma unroll
    for (int nt = 0; nt < 2; ++nt)
#pragma unroll
      for (int reg = 0; reg < 4; ++reg)
        rot[nt][reg] = __shfl(sc[nt][reg], srcl[reg], 64);
#pragma unroll
    for (int nt = 0; nt < 3; ++nt)
#pragma unroll
      for (int reg = 0; reg < 4; ++reg) {
        int row = quad * 4 + reg;
        int jj = nt * 16 + li + row - 15;
        int nthi = (nt > 1) ? 0 : nt;
        int ntlo = (nt == 0) ? 0 : (nt - 1);
        float val = ((li + row) >= 15) ? rot[nthi][reg] : rot[ntlo][reg];
        float s = val + bd[nt][reg];
        if ((unsigned)jj < 32u)
          pw[row * 40 + jj] = __builtin_bit_cast(unsigned short, __float2half(s));
      }
  }
  // epilogue: drain V[31]+mask, finish tile 31
  __builtin_amdgcn_s_waitcnt(0x0F70);
  __syncthreads();
  finish(VS + 2048, nmf);

  // ---- cross-group reduction (red overlays RS region; RS dead) ----
  if (grp == 1) {
    float* rp = red + (size_t)(wq * 64 + lane) * 20;
#pragma unroll
    for (int nt = 0; nt < 4; ++nt)
#pragma unroll
      for (int reg = 0; reg < 4; ++reg) rp[nt * 4 + reg] = o[nt][reg];
#pragma unroll
    for (int reg = 0; reg < 4; ++reg) rp[16 + reg] = ol[reg];
  }
  __syncthreads();
  if (grp == 0) {
    const float* rp = red + (size_t)(wq * 64 + lane) * 20;
    float inv[4];
#pragma unroll
    for (int reg = 0; reg < 4; ++reg) inv[reg] = 1.0f / (ol[reg] + rp[16 + reg]);
#pragma unroll
    for (int nt = 0; nt < 4; ++nt)
#pragma unroll
      for (int reg = 0; reg < 4; ++reg) {
        int trow = t0w + quad * 4 + reg;
        float val = (o[nt][reg] + rp[nt * 4 + reg]) * inv[reg];
        attnb[((size_t)(b * Tq + trow)) * 1024 + h * 64 + nt * 16 + li] = f2bf(val);
      }
  }
}

extern "C" void kernel_launch(void* const* d_in, const int* in_sizes, int n_in,
                              void* d_out, int out_size, void* d_ws, size_t ws_size,
                              hipStream_t stream) {
  const float* x = (const float*)d_in[0];
  const float* mask = (const float*)d_in[1];
  const float* pos = (const float*)d_in[2];
  const float* mem = (const float*)d_in[3];
  const float* Wq = (const float*)d_in[4];
  const float* Wk = (const float*)d_in[5];
  const float* Wv = (const float*)d_in[6];
  const float* Wr = (const float*)d_in[7];
  const float* rwb = (const float*)d_in[8];
  const float* rrb = (const float*)d_in[9];
  const float* Wo = (const float*)d_in[10];
  float* out = (float*)d_out;

  uint8_t* ws = (uint8_t*)d_ws;
  const size_t MB = 1024 * 1024;
  unsigned short* Vinb = (unsigned short*)(ws + 0);
  unsigned short* WqT = (unsigned short*)(ws + 8 * MB);
  unsigned short* WkT = (unsigned short*)(ws + 10 * MB);
  unsigned short* WvT = (unsigned short*)(ws + 12 * MB);
  unsigned short* WrT = (unsigned short*)(ws + 14 * MB);
  unsigned short* WoT = (unsigned short*)(ws + 16 * MB);
  unsigned short* Pb = (unsigned short*)(ws + 18 * MB);
  unsigned short* qb = (unsigned short*)(ws + 24 * MB);
  unsigned short* kb = (unsigned short*)(ws + 32 * MB);
  unsigned short* vtb = (unsigned short*)(ws + 40 * MB);
  unsigned short* rkb = (unsigned short*)(ws + 48 * MB);
  unsigned short* attnb = (unsigned short*)(ws + 19 * MB);

  hipLaunchKernelGGL(k_prep2, dim3(8448), dim3(256), 0, stream,
                     x, mem, pos, Wq, Wk, Wv, Wr, Wo,
                     Vinb, Pb, WqT, WkT, WvT, WrT, WoT);
  hipLaunchKernelGGL(k_proj, dim3(832), dim3(256), 0, stream,
                     Vinb, Pb, WqT, WkT, WvT, WrT, qb, kb, vtb, rkb);
  hipLaunchKernelGGL(k_attn, dim3(16, 16, 2), dim3(512), 0, stream,
                     qb, rwb, rrb, kb, vtb, rkb, mask, attnb);
  hipLaunchKernelGGL(k_gemm_out64, dim3(32, 16), dim3(256), 0, stream,
                     attnb, WoT, out);
}